// Round 4
// baseline (117.730 us; speedup 1.0000x reference)
//
#include <hip/hip_runtime.h>
#include <cstdint>
#include <cstddef>

#define HH 64          // H
#define G2 128         // 2H
#define G3 192         // 3H
#define WROW 65        // floats per weight row
#define ROWF 12480     // 3H*(H+1)
#define BOUNDARY (-0.01f)

__device__ __forceinline__ float sigm(float x) { return 1.0f / (1.0f + __expf(-x)); }

// Zero H_curr, copy c_global into c_global_new.
__global__ __launch_bounds__(256) void init_kernel(float* __restrict__ outH,
                                                   float* __restrict__ outC,
                                                   const float* __restrict__ c_global,
                                                   int fh4) {
    int idx = blockIdx.x * 256 + threadIdx.x;
    int stride = gridDim.x * 256;
    for (int k = idx; k < fh4; k += stride) {
        ((float4*)outH)[k] = make_float4(0.f, 0.f, 0.f, 0.f);
        ((float4*)outC)[k] = ((const float4*)c_global)[k];
    }
}

// One block per gathered feature. Streaming register GEMV:
// group G = t>>4 handles rows G+16k (k=0..11); lane j = t&15 handles
// elements j, j+16, j+32, j+48 (+ lane 0: element 64).
__global__ __launch_bounds__(256) void lstm_main(
    const float* __restrict__ X, const float* __restrict__ delta,
    const float* __restrict__ Ht, const float* __restrict__ c_t,
    const float* __restrict__ W, const float* __restrict__ bias,
    const float* __restrict__ xTw, const float* __restrict__ xTb,
    const float* __restrict__ dTw, const float* __restrict__ cinw,
    const float* __restrict__ coutw, const int* __restrict__ feat_idx,
    float* __restrict__ outH, float* __restrict__ outC) {

    __shared__ __align__(16) float inp[68];   // [x, h_prev(64)]
    __shared__ float co[G3];

    const int t = threadIdx.x;
    const int i = feat_idx[blockIdx.x];
    const size_t i1 = (size_t)i * HH;
    const size_t i2 = (size_t)i * G2;
    const size_t i3 = (size_t)i * G3;

    // register prefetch of all gate-phase operands (t<64); loads issue early,
    // latency hides under the streaming dot loop
    float xi = 0.f, di = 0.f, ct = 0.f, cinv = 0.f, coutv = 0.f;
    float xw1 = 0.f, xw2 = 0.f, xb1 = 0.f, xb2 = 0.f;
    float dw1 = 0.f, dw2 = 0.f, dwo = 0.f, b0 = 0.f, b1 = 0.f, b2 = 0.f;
    if (t < HH) {
        xi = X[i];  di = delta[i];  ct = c_t[t];
        cinv = cinw[i1 + t];  coutv = coutw[i1 + t];
        xw1 = xTw[i2 + t];  xw2 = xTw[i2 + HH + t];
        xb1 = xTb[i2 + t];  xb2 = xTb[i2 + HH + t];
        dw1 = dTw[i3 + t];  dw2 = dTw[i3 + HH + t];  dwo = dTw[i3 + 2 * HH + t];
        b0 = bias[i3 + t];  b1 = bias[i3 + HH + t];  b2 = bias[i3 + 2 * HH + t];
    }

    // stage cur_input = [x, h_prev]
    if (t == 0) inp[0] = X[i];
    if (t >= 64 && t < 128) inp[1 + (t - 64)] = Ht[i1 + (t - 64)];
    __syncthreads();

    // ---- streaming dot phase (no LDS staging of W) ----
    {
        const int G = t >> 4, j = t & 15;
        const float in0 = inp[j], in1 = inp[j + 16], in2 = inp[j + 32], in3 = inp[j + 48];
        const float in4 = inp[64];                       // used by lane j==0 only
        const float* wp = W + (size_t)i * ROWF + G * WROW + j;
        #pragma unroll 4
        for (int k = 0; k < 12; ++k) {
            const float* wr = wp + k * (16 * WROW);
            float acc = wr[0] * in0;
            acc = fmaf(wr[16], in1, acc);
            acc = fmaf(wr[32], in2, acc);
            acc = fmaf(wr[48], in3, acc);
            if (j == 0) acc = fmaf(wr[64 - j], in4, acc);   // element 64 (wr points at j=0)
            // 16-lane butterfly reduce
            acc += __shfl_xor(acc, 1);
            acc += __shfl_xor(acc, 2);
            acc += __shfl_xor(acc, 4);
            acc += __shfl_xor(acc, 8);
            if (j == 0) co[G + 16 * k] = acc;
        }
    }
    __syncthreads();

    // ---- gate math: 64 threads ----
    if (t < HH) {
        float gi_pre = co[t] + b0;
        float go_pre = co[HH + t] + b1;
        float gc     = tanhf(co[2 * HH + t] + b2);

        float xm1 = fmaf(xw1, xi, xb1);
        float xm2 = fmaf(xw2, xi, xb2);
        if (t == 0) dw2 = fminf(dw2, BOUNDARY);   // clip delT row H (elem 0 of T2 block)

        float T1 = sigm(xm1 + sigm(dw1 * di));
        float T2 = sigm(xm2 + sigm(dw2 * di));
        float gi = sigm(gi_pre + cinv * ct);

        float gT1     = gi * T1;
        float c_tilde = (1.f - gT1) * ct + gT1 * gc;
        float c_new   = (1.f - gi) * ct + gi * T2 * gc;
        float go      = sigm(go_pre + coutv * c_tilde + dwo * di);

        outH[i1 + t] = go * tanhf(c_tilde);
        outC[i1 + t] = c_new;
    }
}

// Stage 1: 64 gathered rows per block -> 64 partials per block.
__global__ __launch_bounds__(256) void reduceA(const float* __restrict__ outC,
                                               const int* __restrict__ feat_idx,
                                               float* __restrict__ partial, int n) {
    __shared__ float s[256];
    const int b = blockIdx.x, t = threadIdx.x;
    const int h = t & 63, g = t >> 6;
    const int rend = min(n, (b + 1) * 64);
    float acc = 0.f;
    for (int r = b * 64 + g; r < rend; r += 4)
        acc += outC[(size_t)feat_idx[r] * HH + h];
    s[t] = acc;
    __syncthreads();
    if (t < HH) partial[b * HH + h] = s[h] + s[64 + h] + s[128 + h] + s[192 + h];
}

// Stage 2: combine block partials, divide by n.
__global__ __launch_bounds__(256) void reduceB(const float* __restrict__ partial,
                                               float* __restrict__ outM,
                                               int nblocks, int n) {
    __shared__ float s[256];
    const int t = threadIdx.x, h = t & 63, g = t >> 6;
    float acc = 0.f;
    for (int b = g; b < nblocks; b += 4) acc += partial[(size_t)b * HH + h];
    s[t] = acc;
    __syncthreads();
    if (t < HH) outM[h] = (s[h] + s[64 + h] + s[128 + h] + s[192 + h]) / (float)n;
}

// Fallback if d_ws too small: single-block deterministic reduce.
__global__ __launch_bounds__(256) void reduceAll(const float* __restrict__ outC,
                                                 const int* __restrict__ feat_idx,
                                                 float* __restrict__ outM, int n) {
    __shared__ float s[256];
    const int t = threadIdx.x, h = t & 63, g = t >> 6;
    float acc = 0.f;
    for (int r = g; r < n; r += 4)
        acc += outC[(size_t)feat_idx[r] * HH + h];
    s[t] = acc;
    __syncthreads();
    if (t < HH) outM[h] = (s[h] + s[64 + h] + s[128 + h] + s[192 + h]) / (float)n;
}

extern "C" void kernel_launch(void* const* d_in, const int* in_sizes, int n_in,
                              void* d_out, int out_size, void* d_ws, size_t ws_size,
                              hipStream_t stream) {
    const float* X        = (const float*)d_in[0];
    const float* delta    = (const float*)d_in[1];
    const float* Ht       = (const float*)d_in[2];
    const float* c_t      = (const float*)d_in[3];
    const float* c_global = (const float*)d_in[4];
    const float* W        = (const float*)d_in[5];
    const float* bias     = (const float*)d_in[6];
    const float* xTw      = (const float*)d_in[7];
    const float* xTb      = (const float*)d_in[8];
    const float* dTw      = (const float*)d_in[9];
    const float* cinw     = (const float*)d_in[10];
    const float* coutw    = (const float*)d_in[11];
    const int*   feat_idx = (const int*)d_in[12];

    const int F  = in_sizes[0];
    const int n  = in_sizes[12];
    const int FH = F * HH;

    float* out  = (float*)d_out;
    float* outH = out;            // [F,H]
    float* outC = out + FH;       // [F,H]
    float* outM = out + 2 * FH;   // [H]

    // init: zero H_curr, copy c_global
    {
        int fh4 = FH / 4;
        int blocks = (fh4 + 255) / 256;
        if (blocks > 2048) blocks = 2048;
        init_kernel<<<blocks, 256, 0, stream>>>(outH, outC, c_global, fh4);
    }

    // main: one block per gathered feature, streaming GEMV
    lstm_main<<<n, 256, 0, stream>>>(X, delta, Ht, c_t, W, bias, xTw, xTb,
                                     dTw, cinw, coutw, feat_idx, outH, outC);

    // mean reduction (deterministic, 2-stage)
    int nA = (n + 63) / 64;
    if (ws_size >= (size_t)nA * HH * sizeof(float)) {
        float* partial = (float*)d_ws;
        reduceA<<<nA, 256, 0, stream>>>(outC, feat_idx, partial, n);
        reduceB<<<1, 256, 0, stream>>>(partial, outM, nA, n);
    } else {
        reduceAll<<<1, 256, 0, stream>>>(outC, feat_idx, outM, n);
    }
}